// Round 1
// baseline (76.875 us; speedup 1.0000x reference)
//
#include <hip/hip_runtime.h>

#define T_LEN 1024
#define N_ORD 64

// Kernel A: KT2 layout: element ((t>>2)*64 + n)*4 + (t&3) = K[n][1023 - t]
// One float4 per thread, coalesced writes; reads are per-lane contiguous
// (reversed) float4 from K. 16384 threads total.
__global__ __launch_bounds__(256) void build_kt(const float* __restrict__ K,
                                                float4* __restrict__ KT2) {
    int g  = blockIdx.x * 256 + threadIdx.x;   // 0..16383
    int t4 = g >> 6;                           // t-group (4 t's per group)
    int n  = g & 63;
    // K[n][1020-4t4 .. 1023-4t4]  (aligned 16B since offset % 4 == 0)
    const float4 kv = *(const float4*)(K + n * T_LEN + (1020 - 4 * t4));
    // reverse so .x = kt(4t4), .y = kt(4t4+1), ...
    KT2[g] = make_float4(kv.w, kv.z, kv.y, kv.x);
}

// Kernel B: block handles 4 rows x all 64 n x full T.
// thread: n = tid&63, q = tid>>6 (t-quarter), 4 row-accumulators.
__global__ __launch_bounds__(256) void hippo_last(const float* __restrict__ u,
                                                  const float4* __restrict__ KT2,
                                                  float* __restrict__ out) {
    __shared__ float4 u4[4 * 256];      // 4 rows x 1024 floats = 16 KB
    __shared__ float red[4][4][64];     // [q][r][n] = 4 KB

    const int tid   = threadIdx.x;
    const int rows0 = blockIdx.x * 4;   // 128 blocks x 4 rows = 512 rows

    // stage 4 contiguous rows (4096 floats) into LDS, fully coalesced
    const float4* src = (const float4*)(u + rows0 * T_LEN);
    #pragma unroll
    for (int k = 0; k < 4; ++k) u4[tid + k * 256] = src[tid + k * 256];
    __syncthreads();

    const int n = tid & 63;
    const int q = tid >> 6;

    float acc0 = 0.f, acc1 = 0.f, acc2 = 0.f, acc3 = 0.f;
    #pragma unroll 4
    for (int t4 = q * 64; t4 < q * 64 + 64; ++t4) {
        const float4 kf = KT2[t4 * 64 + n];   // coalesced across lanes
        const float4 u0 = u4[0 * 256 + t4];   // wave-uniform broadcast reads
        const float4 u1 = u4[1 * 256 + t4];
        const float4 u2 = u4[2 * 256 + t4];
        const float4 u3 = u4[3 * 256 + t4];
        acc0 += u0.x * kf.x + u0.y * kf.y + u0.z * kf.z + u0.w * kf.w;
        acc1 += u1.x * kf.x + u1.y * kf.y + u1.z * kf.z + u1.w * kf.w;
        acc2 += u2.x * kf.x + u2.y * kf.y + u2.z * kf.z + u2.w * kf.w;
        acc3 += u3.x * kf.x + u3.y * kf.y + u3.z * kf.z + u3.w * kf.w;
    }

    red[q][0][n] = acc0;
    red[q][1][n] = acc1;
    red[q][2][n] = acc2;
    red[q][3][n] = acc3;
    __syncthreads();

    // cross-quarter reduction; tid -> (r = tid>>6, n2 = tid&63)
    const int r  = tid >> 6;
    const int n2 = tid & 63;
    float v = red[0][r][n2] + red[1][r][n2] + red[2][r][n2] + red[3][r][n2];
    out[rows0 * 64 + tid] = v;   // 1 KB fully-coalesced store per block
}

extern "C" void kernel_launch(void* const* d_in, const int* in_sizes, int n_in,
                              void* d_out, int out_size, void* d_ws, size_t ws_size,
                              hipStream_t stream) {
    const float* inputs = (const float*)d_in[0];   // (4,2,64,1024) fp32
    const float* K      = (const float*)d_in[1];   // (64,1024) fp32
    float* out  = (float*)d_out;                   // (4,2,64,64) fp32
    float4* KT2 = (float4*)d_ws;                   // 256 KB scratch

    build_kt<<<64, 256, 0, stream>>>(K, KT2);
    hippo_last<<<128, 256, 0, stream>>>(inputs, KT2, out);
}

// Round 2
// 62.028 us; speedup vs baseline: 1.2394x; 1.2394x over previous
//
#include <hip/hip_runtime.h>

#define T_LEN 1024
#define N_ORD 64

// Kernel A: KT2 layout: element ((t>>2)*64 + n)*4 + (t&3) = K[n][1023 - t]
// One float4 per thread, coalesced writes; reads are per-lane contiguous
// (reversed) float4 from K. 16384 threads total.
__global__ __launch_bounds__(256) void build_kt(const float* __restrict__ K,
                                                float4* __restrict__ KT2) {
    int g  = blockIdx.x * 256 + threadIdx.x;   // 0..16383
    int t4 = g >> 6;                           // t-group (4 t's per group)
    int n  = g & 63;
    // K[n][1020-4t4 .. 1023-4t4]  (aligned 16B since offset % 4 == 0)
    const float4 kv = *(const float4*)(K + n * T_LEN + (1020 - 4 * t4));
    // reverse so .x = kt(4t4), .y = kt(4t4+1), ...
    KT2[g] = make_float4(kv.w, kv.z, kv.y, kv.x);
}

// Kernel B: block handles 2 rows x all 64 n x full T. 256 blocks -> 1/CU.
// thread: n = tid&63, q = tid>>6 (t-quarter), 2 row-accumulators.
// Pipes: KT2 streams via vector-memory/L2 (64 b128/wave), u via LDS
// broadcast (128 b128/wave, same-address => conflict-free), FMA on VALU.
__global__ __launch_bounds__(256) void hippo_last(const float* __restrict__ u,
                                                  const float4* __restrict__ KT2,
                                                  float* __restrict__ out) {
    __shared__ float4 u4[2 * 256];      // 2 rows x 1024 floats = 8 KB
    __shared__ float red[4][2][64];     // [q][r][n] = 2 KB

    const int tid   = threadIdx.x;
    const int rows0 = blockIdx.x * 2;   // 256 blocks x 2 rows = 512 rows

    // stage 2 contiguous rows (2048 floats = 512 float4) coalesced
    const float4* src = (const float4*)(u + rows0 * T_LEN);
    u4[tid]       = src[tid];
    u4[tid + 256] = src[tid + 256];
    __syncthreads();

    const int n = tid & 63;
    const int q = tid >> 6;

    float acc0 = 0.f, acc1 = 0.f;
    #pragma unroll 8
    for (int t4 = q * 64; t4 < q * 64 + 64; ++t4) {
        const float4 kf = KT2[t4 * 64 + n];   // coalesced across lanes, L2-fed
        const float4 u0 = u4[t4];             // wave-uniform broadcast reads
        const float4 u1 = u4[256 + t4];
        acc0 += u0.x * kf.x + u0.y * kf.y + u0.z * kf.z + u0.w * kf.w;
        acc1 += u1.x * kf.x + u1.y * kf.y + u1.z * kf.z + u1.w * kf.w;
    }

    red[q][0][n] = acc0;
    red[q][1][n] = acc1;
    __syncthreads();

    // cross-quarter reduction; threads 0..127 -> (r = tid>>6, n2 = tid&63)
    if (tid < 128) {
        const int r  = tid >> 6;
        const int n2 = tid & 63;
        out[rows0 * 64 + tid] = red[0][r][n2] + red[1][r][n2] +
                                red[2][r][n2] + red[3][r][n2];
    }
}

extern "C" void kernel_launch(void* const* d_in, const int* in_sizes, int n_in,
                              void* d_out, int out_size, void* d_ws, size_t ws_size,
                              hipStream_t stream) {
    const float* inputs = (const float*)d_in[0];   // (4,2,64,1024) fp32
    const float* K      = (const float*)d_in[1];   // (64,1024) fp32
    float* out  = (float*)d_out;                   // (4,2,64,64) fp32
    float4* KT2 = (float4*)d_ws;                   // 256 KB scratch

    build_kt<<<64, 256, 0, stream>>>(K, KT2);
    hippo_last<<<256, 256, 0, stream>>>(inputs, KT2, out);
}